// Round 3
// baseline (59081.989 us; speedup 1.0000x reference)
//
#include <hip/hip_runtime.h>

// ---- guide-verbatim ds_swizzle XOR butterfly (bit-uniform across lanes) --
// BitMode offset = (xor_mask<<10) | (or_mask<<5) | and_mask; and=0x1F keeps
// all 5 lane bits; operates independently within each 32-lane half.

template<int OFF>
__device__ __forceinline__ float swz_add(float v) {
    int s = __builtin_amdgcn_ds_swizzle(__float_as_int(v), OFF);
    return v + __int_as_float(s);
}

// sum over the 32 lanes of this half (lanes 0-31 or 32-63); every lane of the
// half gets a BIT-IDENTICAL result (xor pairing is commutative-exact).
__device__ __forceinline__ float red32(float v) {
    v = swz_add<0x041F>(v);  // lane ^ 1
    v = swz_add<0x081F>(v);  // lane ^ 2
    v = swz_add<0x101F>(v);  // lane ^ 4
    v = swz_add<0x201F>(v);  // lane ^ 8
    v = swz_add<0x401F>(v);  // lane ^ 16
    return v;
}

// ---- DDLMS scan kernel: one wave64; half h = output dim i ---------------

__global__ __launch_bounds__(64, 1)
void ddlms_scan(const float* __restrict__ xre,
                const float* __restrict__ xim,
                float* __restrict__ out) {
    const int l = (int)threadIdx.x;
    const int m = l & 31;              // element index within half-frame
    const int half = l >> 5;           // output dim i owned by this half

    constexpr float EPSv = 1e-8f;
    constexpr float LRW  = 1.0f / 64.0f;
    constexpr float LRF  = 1.0f / 128.0f;
    constexpr float LRB  = 1.0f / 2048.0f;
    const float B1 = 0.6324555320336759f;   // 2/sqrt(10)
    const float A1 = 0.31622776601683794f;  // 1/sqrt(10)
    const float A3 = 0.9486832980505138f;   // 3/sqrt(10)

    // per-lane state: two taps w[i][j][tA], w[i][j][tB]; i=half, j=m&1, tA=m>>1
    float wAr = 0.f, wAi = 0.f, wBr = 0.f, wBi = 0.f;
    // per-half scalar state (bit-uniform within the half)
    float fr = 1.f, fi = 0.f, br = 0.f, bi = 0.f;

    float2* __restrict__ o2 = reinterpret_cast<float2*>(out);
    const int NS = 99985;

    auto LOADU = [&](int nn, float& ar, float& ai, float& brr, float& bii) {
        const float* pr = xre + 4 * nn;
        const float* pi = xim + 4 * nn;
        ar  = pr[m];        brr = pr[m + 32];
        ai  = pi[m];        bii = pi[m + 32];
    };

    auto STEP = [&](int n, float uAr, float uAi, float uBr, float uBi) {
        // this lane's 2 taps' contribution to v_i, and |u|^2 partial
        float prr = wAr * uAr; prr = fmaf(-wAi, uAi, prr);
        prr = fmaf(wBr, uBr, prr); prr = fmaf(-wBi, uBi, prr);
        float pri = wAr * uAi; pri = fmaf( wAi, uAr, pri);
        pri = fmaf(wBr, uBi, pri); pri = fmaf( wBi, uBr, pri);
        float uu  = uAr * uAr; uu = fmaf(uAi, uAi, uu);
        uu = fmaf(uBr, uBr, uu); uu = fmaf(uBi, uBi, uu);

        float vr = red32(prr);
        float vi = red32(pri);
        float un = red32(uu);

        // k = v*f ; z = k + b   (z is also the step output y[n])
        float kr = fmaf(vr, fr, -(vi * fi));
        float ki = fmaf(vr, fi,   vi * fr);
        float zr = kr + br, zi = ki + bi;
        if (m == 0) o2[2 * n + half] = make_float2(zr, zi);

        // 16-QAM slicer (ties -> more-negative symbol, matching argmin order)
        float magr = (fabsf(zr) > B1) ? A3 : A1;
        float dr   = (zr <= 0.f) ? -magr : magr;
        float magi = (fabsf(zi) > B1) ? A3 : A1;
        float di   = (zi <= 0.f) ? -magi : magi;

        float er = dr - zr, ei = di - zi;        // e_f = e_b = e

        // f grad (positive sense): gf = e*conj(v)/(|v|^2+eps), clip at 30
        float v2  = fmaf(vr, vr, fmaf(vi, vi, EPSv));
        float rv  = 1.0f / v2;
        float gfr = fmaf(er, vr,   ei * vi)  * rv;
        float gfi = fmaf(ei, vr, -(er * vi)) * rv;
        float ag  = sqrtf(fmaf(gfr, gfr, gfi * gfi));
        float scf = fminf(1.f, 30.f / fmaxf(ag, 1e-30f));

        // psi = conj(f)/|f|   (OLD f)
        float ff  = fmaf(fr, fr, fi * fi);
        float rs  = 1.0f / sqrtf(ff);
        float psr =   fr * rs;
        float psj = -(fi * rs);

        // db = d - b (OLD b);  e_w = db*psi - v
        float dbr = dr - br, dbi = di - bi;
        float ewr = fmaf(dbr, psr, -(dbi * psj)) - vr;
        float ewi = fmaf(dbr, psj,   dbi * psr)  - vi;

        // state updates (after all uses of old f, b)
        float tf = LRF * scf;
        fr = fmaf(tf, gfr, fr);  fi = fmaf(tf, gfi, fi);
        br = fmaf(LRB, er, br);  bi = fmaf(LRB, ei, bi);

        // w updates: gw = e_w*conj(u)/unorm, per-element clip at 30
        float runo = 1.0f / (un + EPSv);
        float gAr = fmaf(ewr, uAr,   ewi * uAi)  * runo;
        float gAi = fmaf(ewi, uAr, -(ewr * uAi)) * runo;
        float aA  = sqrtf(fmaf(gAr, gAr, gAi * gAi));
        float tA  = LRW * fminf(1.f, 30.f / fmaxf(aA, 1e-30f));
        wAr = fmaf(tA, gAr, wAr); wAi = fmaf(tA, gAi, wAi);

        float gBr = fmaf(ewr, uBr,   ewi * uBi)  * runo;
        float gBi = fmaf(ewi, uBr, -(ewr * uBi)) * runo;
        float aB  = sqrtf(fmaf(gBr, gBr, gBi * gBi));
        float tB  = LRW * fminf(1.f, 30.f / fmaxf(aB, 1e-30f));
        wBr = fmaf(tB, gBr, wBr); wBi = fmaf(tB, gBi, wBi);
    };

    // software pipeline: even/odd u buffers, prefetch ~1.5 steps ahead
    float c0Ar, c0Ai, c0Br, c0Bi, c1Ar, c1Ai, c1Br, c1Bi;
    LOADU(0, c0Ar, c0Ai, c0Br, c0Bi);
    LOADU(1, c1Ar, c1Ai, c1Br, c1Bi);

    int n = 0;
    for (int it = 0; it < 49992; ++it) {
        STEP(n, c0Ar, c0Ai, c0Br, c0Bi);
        int n2 = n + 2; if (n2 > NS - 1) n2 = NS - 1;
        LOADU(n2, c0Ar, c0Ai, c0Br, c0Bi);

        STEP(n + 1, c1Ar, c1Ai, c1Br, c1Bi);
        int n3 = n + 3; if (n3 > NS - 1) n3 = NS - 1;
        LOADU(n3, c1Ar, c1Ai, c1Br, c1Bi);
        n += 2;
    }
    STEP(NS - 1, c0Ar, c0Ai, c0Br, c0Bi);   // step 99984 (odd count tail)
}

extern "C" void kernel_launch(void* const* d_in, const int* in_sizes, int n_in,
                              void* d_out, int out_size, void* d_ws, size_t ws_size,
                              hipStream_t stream) {
    const float* xre = (const float*)d_in[0];
    const float* xim = (const float*)d_in[1];
    float* out = (float*)d_out;
    ddlms_scan<<<1, 64, 0, stream>>>(xre, xim, out);
}

// Round 5
// 51718.677 us; speedup vs baseline: 1.1424x; 1.1424x over previous
//
#include <hip/hip_runtime.h>

// ---- XOR-butterfly reduction: 4 DPP VALU stages + 1 ds_swizzle ----------
// Every stage is an exact XOR pairing (x'_i = x_i + x_{i^m}); fp add is
// commutative, so all 32 lanes of a half hold BIT-IDENTICAL sums after the
// masks {1,2,7,15,16} (span = 5 bits). No permlane asm (R1/R4 bug: "+v"
// operands holding equal values can be register-coalesced, turning the
// two-register swap into an in-place rotate).

template<int CTRL>
__device__ __forceinline__ float dpp_xadd(float v) {
    int s = __builtin_amdgcn_update_dpp(0, __float_as_int(v), CTRL, 0xF, 0xF, true);
    return v + __int_as_float(s);
}

template<int OFF>
__device__ __forceinline__ float swz_add(float v) {
    int s = __builtin_amdgcn_ds_swizzle(__float_as_int(v), OFF);
    return v + __int_as_float(s);
}

// sum over the 32 lanes of this half; bit-identical in every lane of the half
__device__ __forceinline__ float red32(float v) {
    v = dpp_xadd<0xB1>(v);    // quad_perm [1,0,3,2] : lane ^ 1
    v = dpp_xadd<0x4E>(v);    // quad_perm [2,3,0,1] : lane ^ 2
    v = dpp_xadd<0x141>(v);   // row_half_mirror     : lane ^ 7
    v = dpp_xadd<0x140>(v);   // row_mirror          : lane ^ 15
    v = swz_add<0x401F>(v);   // ds_swizzle          : lane ^ 16 (proven, R3)
    return v;
}

// ---- DDLMS scan kernel: one wave64; half h = output dim i ---------------

__global__ __launch_bounds__(64, 1)
void ddlms_scan(const float* __restrict__ xre,
                const float* __restrict__ xim,
                float* __restrict__ out) {
    const int l = (int)threadIdx.x;
    const int m = l & 31;              // element index within half-frame
    const int half = l >> 5;           // output dim i owned by this half

    constexpr float EPSv = 1e-8f;
    constexpr float LRW  = 1.0f / 64.0f;
    constexpr float LRF  = 1.0f / 128.0f;
    constexpr float LRB  = 1.0f / 2048.0f;
    const float B1 = 0.6324555320336759f;   // 2/sqrt(10)
    const float A1 = 0.31622776601683794f;  // 1/sqrt(10)
    const float A3 = 0.9486832980505138f;   // 3/sqrt(10)

    // per-lane state: two taps w[i][j][tA], w[i][j][tB]; i=half, j=m&1, tA=m>>1
    float wAr = 0.f, wAi = 0.f, wBr = 0.f, wBi = 0.f;
    // per-half scalar state (bit-uniform within the half)
    float fr = 1.f, fi = 0.f, br = 0.f, bi = 0.f;

    float2* __restrict__ o2 = reinterpret_cast<float2*>(out);
    const int NS = 99985;

    auto LOADU = [&](int nn, float& ar, float& ai, float& brr, float& bii) {
        const float* pr = xre + 4 * nn;
        const float* pi = xim + 4 * nn;
        ar  = pr[m];        brr = pr[m + 32];
        ai  = pi[m];        bii = pi[m + 32];
    };

    auto STEP = [&](int n, float uAr, float uAi, float uBr, float uBi) {
        // this lane's 2 taps' contribution to v_i, and |u|^2 partial
        float prr = wAr * uAr; prr = fmaf(-wAi, uAi, prr);
        prr = fmaf(wBr, uBr, prr); prr = fmaf(-wBi, uBi, prr);
        float pri = wAr * uAi; pri = fmaf( wAi, uAr, pri);
        pri = fmaf(wBr, uBi, pri); pri = fmaf( wBi, uBr, pri);
        float uu  = uAr * uAr; uu = fmaf(uAi, uAi, uu);
        uu = fmaf(uBr, uBr, uu); uu = fmaf(uBi, uBi, uu);

        float vr = red32(prr);
        float vi = red32(pri);
        float un = red32(uu);

        // k = v*f ; z = k + b   (z is also the step output y[n])
        float kr = fmaf(vr, fr, -(vi * fi));
        float ki = fmaf(vr, fi,   vi * fr);
        float zr = kr + br, zi = ki + bi;
        if (m == 0) o2[2 * n + half] = make_float2(zr, zi);

        // 16-QAM slicer (ties -> more-negative symbol, matching argmin order)
        float magr = (fabsf(zr) > B1) ? A3 : A1;
        float dr   = (zr <= 0.f) ? -magr : magr;
        float magi = (fabsf(zi) > B1) ? A3 : A1;
        float di   = (zi <= 0.f) ? -magi : magi;

        float er = dr - zr, ei = di - zi;        // e_f = e_b = e

        // f grad (positive sense): gf = e*conj(v)/(|v|^2+eps), clip at 30
        float v2  = fmaf(vr, vr, fmaf(vi, vi, EPSv));
        float rv  = 1.0f / v2;
        float gfr = fmaf(er, vr,   ei * vi)  * rv;
        float gfi = fmaf(ei, vr, -(er * vi)) * rv;
        float ag  = sqrtf(fmaf(gfr, gfr, gfi * gfi));
        float scf = fminf(1.f, 30.f / fmaxf(ag, 1e-30f));

        // psi = conj(f)/|f|   (OLD f)
        float ff  = fmaf(fr, fr, fi * fi);
        float rs  = 1.0f / sqrtf(ff);
        float psr =   fr * rs;
        float psj = -(fi * rs);

        // db = d - b (OLD b);  e_w = db*psi - v
        float dbr = dr - br, dbi = di - bi;
        float ewr = fmaf(dbr, psr, -(dbi * psj)) - vr;
        float ewi = fmaf(dbr, psj,   dbi * psr)  - vi;

        // state updates (after all uses of old f, b)
        float tf = LRF * scf;
        fr = fmaf(tf, gfr, fr);  fi = fmaf(tf, gfi, fi);
        br = fmaf(LRB, er, br);  bi = fmaf(LRB, ei, bi);

        // w updates: gw = e_w*conj(u)/unorm, per-element clip at 30
        float runo = 1.0f / (un + EPSv);
        float gAr = fmaf(ewr, uAr,   ewi * uAi)  * runo;
        float gAi = fmaf(ewi, uAr, -(ewr * uAi)) * runo;
        float aA  = sqrtf(fmaf(gAr, gAr, gAi * gAi));
        float tA  = LRW * fminf(1.f, 30.f / fmaxf(aA, 1e-30f));
        wAr = fmaf(tA, gAr, wAr); wAi = fmaf(tA, gAi, wAi);

        float gBr = fmaf(ewr, uBr,   ewi * uBi)  * runo;
        float gBi = fmaf(ewi, uBr, -(ewr * uBi)) * runo;
        float aB  = sqrtf(fmaf(gBr, gBr, gBi * gBi));
        float tB  = LRW * fminf(1.f, 30.f / fmaxf(aB, 1e-30f));
        wBr = fmaf(tB, gBr, wBr); wBi = fmaf(tB, gBi, wBi);
    };

    // software pipeline: even/odd u buffers, prefetch ~1.5 steps ahead
    float c0Ar, c0Ai, c0Br, c0Bi, c1Ar, c1Ai, c1Br, c1Bi;
    LOADU(0, c0Ar, c0Ai, c0Br, c0Bi);
    LOADU(1, c1Ar, c1Ai, c1Br, c1Bi);

    int n = 0;
    for (int it = 0; it < 49992; ++it) {
        STEP(n, c0Ar, c0Ai, c0Br, c0Bi);
        int n2 = n + 2; if (n2 > NS - 1) n2 = NS - 1;
        LOADU(n2, c0Ar, c0Ai, c0Br, c0Bi);

        STEP(n + 1, c1Ar, c1Ai, c1Br, c1Bi);
        int n3 = n + 3; if (n3 > NS - 1) n3 = NS - 1;
        LOADU(n3, c1Ar, c1Ai, c1Br, c1Bi);
        n += 2;
    }
    STEP(NS - 1, c0Ar, c0Ai, c0Br, c0Bi);   // step 99984 (odd count tail)
}

extern "C" void kernel_launch(void* const* d_in, const int* in_sizes, int n_in,
                              void* d_out, int out_size, void* d_ws, size_t ws_size,
                              hipStream_t stream) {
    const float* xre = (const float*)d_in[0];
    const float* xim = (const float*)d_in[1];
    float* out = (float*)d_out;
    ddlms_scan<<<1, 64, 0, stream>>>(xre, xim, out);
}

// Round 6
// 27259.421 us; speedup vs baseline: 2.1674x; 1.8973x over previous
//
#include <hip/hip_runtime.h>

typedef unsigned u2v __attribute__((ext_vector_type(2)));

// ---- XOR-butterfly reduction, all-VALU ----------------------------------
// Exact XOR pairings (commutative-exact): all 32 lanes of a half hold
// BIT-IDENTICAL sums after masks {1,2,7,15,16}.

template<int CTRL>
__device__ __forceinline__ float dpp_xadd(float v) {
    int s = __builtin_amdgcn_update_dpp(0, __float_as_int(v), CTRL, 0xF, 0xF, true);
    return v + __int_as_float(s);
}

#if __has_builtin(__builtin_amdgcn_permlane16_swap)
// v_permlane16_swap_b32 with both operands = v: the two results are
// {x[l], x[l^16]} distributed so r.x + r.y == x[l] + x[l^16] with the SAME
// operand order in both lanes of each pair -> bit-identical. Pure VALU, no
// LDS wait. (The builtin returns both outputs; this is what the R1/R4
// inline-asm version got wrong via register coalescing.)
__device__ __forceinline__ float xor16_add(float v) {
    u2v r = __builtin_amdgcn_permlane16_swap((unsigned)__float_as_int(v),
                                             (unsigned)__float_as_int(v),
                                             false, false);
    return __int_as_float((int)r.x) + __int_as_float((int)r.y);
}
#else
__device__ __forceinline__ float xor16_add(float v) {   // proven fallback (R3)
    int s = __builtin_amdgcn_ds_swizzle(__float_as_int(v), 0x401F);
    return v + __int_as_float(s);
}
#endif

// sum over the 32 lanes of this half; bit-identical in every lane of the half
__device__ __forceinline__ float red32(float v) {
    v = dpp_xadd<0xB1>(v);    // quad_perm [1,0,3,2] : lane ^ 1
    v = dpp_xadd<0x4E>(v);    // quad_perm [2,3,0,1] : lane ^ 2
    v = dpp_xadd<0x141>(v);   // row_half_mirror     : lane ^ 7
    v = dpp_xadd<0x140>(v);   // row_mirror          : lane ^ 15
    v = xor16_add(v);         //                      : lane ^ 16
    return v;
}

// ---- parallel precompute: runo[n] = 1/(sum |u_n|^2 + eps) ---------------
// un depends only on the input (no scan state) -> hoist out of the scan.

__global__ void unorm_pre(const float* __restrict__ xre,
                          const float* __restrict__ xim,
                          float* __restrict__ runo, int ns) {
    int n = blockIdx.x * blockDim.x + threadIdx.x;
    if (n >= ns) return;
    const float* pr = xre + 4 * n;
    const float* pi = xim + 4 * n;
    float s = 0.f;
    #pragma unroll 8
    for (int k = 0; k < 64; ++k) s = fmaf(pr[k], pr[k], s);
    #pragma unroll 8
    for (int k = 0; k < 64; ++k) s = fmaf(pi[k], pi[k], s);
    runo[n] = 1.0f / (s + 1e-8f);
}

// ---- DDLMS scan kernel: one wave64; half h = output dim i ---------------

template<bool PRE>
__global__ __launch_bounds__(64, 1)
void ddlms_scan(const float* __restrict__ xre,
                const float* __restrict__ xim,
                const float* __restrict__ runo_pre,
                float* __restrict__ out) {
    const int l = (int)threadIdx.x;
    const int m = l & 31;              // element index within half-frame
    const int half = l >> 5;           // output dim i owned by this half

    constexpr float EPSv = 1e-8f;
    constexpr float LRW  = 1.0f / 64.0f;
    constexpr float LRF  = 1.0f / 128.0f;
    constexpr float LRB  = 1.0f / 2048.0f;
    const float B1 = 0.6324555320336759f;   // 2/sqrt(10)
    const float A1 = 0.31622776601683794f;  // 1/sqrt(10)
    const float A3 = 0.9486832980505138f;   // 3/sqrt(10)

    // per-lane state: two taps w[i][j][tA], w[i][j][tB]; i=half, j=m&1, tA=m>>1
    float wAr = 0.f, wAi = 0.f, wBr = 0.f, wBi = 0.f;
    // per-half scalar state (bit-uniform within the half)
    float fr = 1.f, fi = 0.f, br = 0.f, bi = 0.f;
    // psi = conj(f)/|f| for the CURRENT f, maintained at end of each step
    float psr = 1.f, psj = 0.f;

    float2* __restrict__ o2 = reinterpret_cast<float2*>(out);
    const int NS = 99985;

    auto LOADU = [&](int nn, float& ar, float& ai, float& brr, float& bii,
                     float& rno) {
        const float* pr = xre + 4 * nn;
        const float* pi = xim + 4 * nn;
        ar  = pr[m];        brr = pr[m + 32];
        ai  = pi[m];        bii = pi[m + 32];
        if constexpr (PRE) rno = runo_pre[nn];
    };

    auto STEP = [&](int n, float uAr, float uAi, float uBr, float uBi,
                    float rno) {
        // this lane's 2 taps' contribution to v_i
        float prr = wAr * uAr; prr = fmaf(-wAi, uAi, prr);
        prr = fmaf(wBr, uBr, prr); prr = fmaf(-wBi, uBi, prr);
        float pri = wAr * uAi; pri = fmaf( wAi, uAr, pri);
        pri = fmaf(wBr, uBi, pri); pri = fmaf( wBi, uBr, pri);

        float vr = red32(prr);
        float vi = red32(pri);

        float runo;
        if constexpr (PRE) {
            runo = rno;
        } else {
            float uu = uAr * uAr; uu = fmaf(uAi, uAi, uu);
            uu = fmaf(uBr, uBr, uu); uu = fmaf(uBi, uBi, uu);
            runo = __builtin_amdgcn_rcpf(red32(uu) + EPSv);
        }

        // k = v*f ; z = k + b   (z is also the step output y[n])
        float kr = fmaf(vr, fr, -(vi * fi));
        float ki = fmaf(vr, fi,   vi * fr);
        float zr = kr + br, zi = ki + bi;
        if (m == 0) o2[2 * n + half] = make_float2(zr, zi);

        // 16-QAM slicer (ties -> more-negative symbol, matching argmin order)
        float magr = (fabsf(zr) > B1) ? A3 : A1;
        float dr   = (zr <= 0.f) ? -magr : magr;
        float magi = (fabsf(zi) > B1) ? A3 : A1;
        float di   = (zi <= 0.f) ? -magi : magi;

        float er = dr - zr, ei = di - zi;        // e_f = e_b = e

        // f grad: gf = e*conj(v)/(|v|^2+eps), clip at 30 via rsq
        float v2  = fmaf(vr, vr, fmaf(vi, vi, EPSv));
        float rv  = __builtin_amdgcn_rcpf(v2);
        float gfr = fmaf(er, vr,   ei * vi)  * rv;
        float gfi = fmaf(ei, vr, -(er * vi)) * rv;
        float m2  = fmaf(gfr, gfr, gfi * gfi);
        float scf = fminf(1.f, 30.f * __builtin_amdgcn_rsqf(m2));  // m2=0 -> 1

        // db = d - b (OLD b);  e_w = db*psi - v   (psi from OLD f, hoisted)
        float dbr = dr - br, dbi = di - bi;
        float ewr = fmaf(dbr, psr, -(dbi * psj)) - vr;
        float ewi = fmaf(dbr, psj,   dbi * psr)  - vi;

        // state updates (after all uses of old f, b)
        float tf = LRF * scf;
        fr = fmaf(tf, gfr, fr);  fi = fmaf(tf, gfi, fi);
        br = fmaf(LRB, er, br);  bi = fmaf(LRB, ei, bi);

        // psi for NEXT step (off the next step's critical path)
        float ff  = fmaf(fr, fr, fi * fi);
        float rs  = __builtin_amdgcn_rsqf(ff);
        psr =   fr * rs;
        psj = -(fi * rs);

        // w updates: gw = e_w*conj(u)*runo, per-element clip at 30 via rsq
        float gAr = fmaf(ewr, uAr,   ewi * uAi)  * runo;
        float gAi = fmaf(ewi, uAr, -(ewr * uAi)) * runo;
        float mA  = fmaf(gAr, gAr, gAi * gAi);
        float tA  = LRW * fminf(1.f, 30.f * __builtin_amdgcn_rsqf(mA));
        wAr = fmaf(tA, gAr, wAr); wAi = fmaf(tA, gAi, wAi);

        float gBr = fmaf(ewr, uBr,   ewi * uBi)  * runo;
        float gBi = fmaf(ewi, uBr, -(ewr * uBi)) * runo;
        float mB  = fmaf(gBr, gBr, gBi * gBi);
        float tB  = LRW * fminf(1.f, 30.f * __builtin_amdgcn_rsqf(mB));
        wBr = fmaf(tB, gBr, wBr); wBi = fmaf(tB, gBi, wBi);
    };

    // software pipeline: even/odd u buffers, prefetch ~1.5 steps ahead
    float c0Ar, c0Ai, c0Br, c0Bi, r0 = 0.f;
    float c1Ar, c1Ai, c1Br, c1Bi, r1 = 0.f;
    LOADU(0, c0Ar, c0Ai, c0Br, c0Bi, r0);
    LOADU(1, c1Ar, c1Ai, c1Br, c1Bi, r1);

    int n = 0;
    for (int it = 0; it < 49992; ++it) {
        STEP(n, c0Ar, c0Ai, c0Br, c0Bi, r0);
        int n2 = n + 2; if (n2 > NS - 1) n2 = NS - 1;
        LOADU(n2, c0Ar, c0Ai, c0Br, c0Bi, r0);

        STEP(n + 1, c1Ar, c1Ai, c1Br, c1Bi, r1);
        int n3 = n + 3; if (n3 > NS - 1) n3 = NS - 1;
        LOADU(n3, c1Ar, c1Ai, c1Br, c1Bi, r1);
        n += 2;
    }
    STEP(NS - 1, c0Ar, c0Ai, c0Br, c0Bi, r0);   // step 99984 (odd count tail)
}

extern "C" void kernel_launch(void* const* d_in, const int* in_sizes, int n_in,
                              void* d_out, int out_size, void* d_ws, size_t ws_size,
                              hipStream_t stream) {
    const float* xre = (const float*)d_in[0];
    const float* xim = (const float*)d_in[1];
    float* out = (float*)d_out;
    const int NS = 99985;

    if (ws_size >= (size_t)NS * sizeof(float)) {
        float* runo = (float*)d_ws;
        unorm_pre<<<(NS + 255) / 256, 256, 0, stream>>>(xre, xim, runo, NS);
        ddlms_scan<true><<<1, 64, 0, stream>>>(xre, xim, runo, out);
    } else {
        ddlms_scan<false><<<1, 64, 0, stream>>>(xre, xim, nullptr, out);
    }
}

// Round 8
// 23381.371 us; speedup vs baseline: 2.5269x; 1.1659x over previous
//
#include <hip/hip_runtime.h>

typedef unsigned u2v __attribute__((ext_vector_type(2)));

// ---- XOR-butterfly reduction, all-VALU (proven bit-uniform, R5/R6) ------
template<int CTRL>
__device__ __forceinline__ float dpp_xadd(float v) {
    int s = __builtin_amdgcn_update_dpp(0, __float_as_int(v), CTRL, 0xF, 0xF, true);
    return v + __int_as_float(s);
}

#if __has_builtin(__builtin_amdgcn_permlane16_swap)
__device__ __forceinline__ float xor16_add(float v) {
    u2v r = __builtin_amdgcn_permlane16_swap((unsigned)__float_as_int(v),
                                             (unsigned)__float_as_int(v),
                                             false, false);
    return __int_as_float((int)r.x) + __int_as_float((int)r.y);
}
#else
__device__ __forceinline__ float xor16_add(float v) {   // proven fallback (R3)
    int s = __builtin_amdgcn_ds_swizzle(__float_as_int(v), 0x401F);
    return v + __int_as_float(s);
}
#endif

__device__ __forceinline__ float red32(float v) {
    v = dpp_xadd<0xB1>(v);    // lane ^ 1
    v = dpp_xadd<0x4E>(v);    // lane ^ 2
    v = dpp_xadd<0x141>(v);   // lane ^ 7
    v = dpp_xadd<0x140>(v);   // lane ^ 15
    v = xor16_add(v);         // lane ^ 16
    return v;
}

// ---- parallel precompute: s_n = LRW/(sum|u_n|^2+eps); sC_n = s_n*C_n ----
// C_n = sum_k conj(u_n[k]) * u_{n+1}[k]   (input-only, no scan state)
__global__ void pre_tab(const float* __restrict__ xre,
                        const float* __restrict__ xim,
                        float4* __restrict__ tab, int ns) {
    int n = blockIdx.x * blockDim.x + threadIdx.x;
    if (n >= ns) return;
    const float* ar = xre + 4 * n;
    const float* ai = xim + 4 * n;
    float un = 0.f;
    #pragma unroll 8
    for (int k = 0; k < 64; ++k) un = fmaf(ar[k], ar[k], fmaf(ai[k], ai[k], un));
    float s = (1.0f / 64.0f) / (un + 1e-8f);
    float cr = 0.f, ci = 0.f;
    if (n + 1 < ns) {
        const float* br_ = ar + 4;
        const float* bi_ = ai + 4;
        #pragma unroll 8
        for (int k = 0; k < 64; ++k) {
            cr = fmaf(ar[k], br_[k], fmaf(ai[k], bi_[k], cr));
            ci = fmaf(ar[k], bi_[k], ci);
            ci = fmaf(-ai[k], br_[k], ci);
        }
    }
    tab[n] = make_float4(s, s * cr, s * ci, 0.f);
}

// ---- DDLMS scan: one wave64; half = output dim; v split base+delta ------
template<bool PRE>
__global__ __launch_bounds__(64, 1)
void ddlms_scan(const float* __restrict__ xre,
                const float* __restrict__ xim,
                const float4* __restrict__ tab,
                float* __restrict__ out) {
    const int l = (int)threadIdx.x;
    const int m = l & 31;
    const int half = l >> 5;

    constexpr float EPSv = 1e-8f;
    constexpr float LRW  = 1.0f / 64.0f;
    constexpr float LRF  = 1.0f / 128.0f;
    constexpr float LRB  = 1.0f / 2048.0f;
    const float B1 = 0.6324555320336759f;
    const float A1 = 0.31622776601683794f;
    const float A3 = 0.9486832980505138f;

    float wAr=0.f, wAi=0.f, wBr=0.f, wBi=0.f;          // 2 taps/lane
    float fr=1.f, fi=0.f, br=0.f, bi=0.f;              // per-half scalars
    float psr=1.f, psj=0.f;                            // conj(f)/|f|
    float vr=0.f, vi=0.f;                              // v for upcoming step
    float ewPr=0.f, ewPi=0.f, sP=0.f;                  // prev step's ew, s

    float2* __restrict__ o2 = reinterpret_cast<float2*>(out);
    const int NS = 99985;

    auto LOADU = [&](int nn, float& a, float& b_, float& c, float& d_) {
        const float* pr = xre + 4 * nn;
        const float* pi = xim + 4 * nn;
        a = pr[m]; c = pr[m + 32]; b_ = pi[m]; d_ = pi[m + 32];
    };

    // three rotating u-buffers: roles P=u_{n-1}, C=u_n, N=u_{n+1}
    float pAr, pAi, pBr, pBi;
    float qAr, qAi, qBr, qBi;
    float rAr, rAi, rBr, rBi;
    pAr = pAi = pBr = pBi = 0.f;        // u_{-1}: unused (sP=0)
    LOADU(0, qAr, qAi, qBr, qBi);
    LOADU(1, rAr, rAi, rBr, rBi);

    auto STEP = [&](int n,
        float& uPAr, float& uPAi, float& uPBr, float& uPBi,
        float& uCAr, float& uCAi, float& uCBr, float& uCBi,
        float& uNAr, float& uNAi, float& uNBr, float& uNBi) {

        // shadow: apply previous step's w-delta: w += sP*(ewP (x) conj(uP))
        {
            float gr = ewPr * uPAr; gr = fmaf( ewPi, uPAi, gr);
            float gi = ewPi * uPAr; gi = fmaf(-ewPr, uPAi, gi);
            wAr = fmaf(sP, gr, wAr); wAi = fmaf(sP, gi, wAi);
            float hr = ewPr * uPBr; hr = fmaf( ewPi, uPBi, hr);
            float hi = ewPi * uPBr; hi = fmaf(-ewPr, uPBi, hi);
            wBr = fmaf(sP, hr, wBr); wBi = fmaf(sP, hi, wBi);
        }

        // shadow: base_{n+1} = red(w_n * u_{n+1})
        float basr, basi;
        {
            float prr = wAr * uNAr; prr = fmaf(-wAi, uNAi, prr);
            prr = fmaf(wBr, uNBr, prr); prr = fmaf(-wBi, uNBi, prr);
            float pri = wAr * uNAi; pri = fmaf( wAi, uNAr, pri);
            pri = fmaf(wBr, uNBi, pri); pri = fmaf( wBi, uNBr, pri);
            basr = red32(prr); basi = red32(pri);
        }

        // per-step scalars s_n, sC_n
        float sN, sCr, sCi;
        if constexpr (PRE) {
            float4 t = tab[n];
            sN = t.x; sCr = t.y; sCi = t.z;
        } else {
            float uu = uCAr * uCAr; uu = fmaf(uCAi, uCAi, uu);
            uu = fmaf(uCBr, uCBr, uu); uu = fmaf(uCBi, uCBi, uu);
            sN = LRW * __builtin_amdgcn_rcpf(red32(uu) + EPSv);
            float ccr = uCAr * uNAr; ccr = fmaf(uCAi, uNAi, ccr);
            ccr = fmaf(uCBr, uNBr, ccr); ccr = fmaf(uCBi, uNBi, ccr);
            float cci = uCAr * uNAi; cci = fmaf(-uCAi, uNAr, cci);
            cci = fmaf(uCBr, uNBi, cci); cci = fmaf(-uCBi, uNBr, cci);
            sCr = sN * red32(ccr); sCi = sN * red32(cci);
        }

        // ---- critical chain ----
        float kr = fmaf(vr, fr, -(vi * fi));
        float ki = fmaf(vr, fi,   vi * fr);
        float zr = kr + br, zi = ki + bi;
        if (m == 0) o2[2 * n + half] = make_float2(zr, zi);

        float magr = (fabsf(zr) > B1) ? A3 : A1;
        float dr   = (zr <= 0.f) ? -magr : magr;
        float magi = (fabsf(zi) > B1) ? A3 : A1;
        float di   = (zi <= 0.f) ? -magi : magi;

        float er = dr - zr, ei = di - zi;

        // f-chain: EXACT clip test m2 = |gf|^2 (R6-proven; the e2*rv
        // surrogate deviated % -level in the early clipped phase -> R7 fail)
        float v2  = fmaf(vr, vr, fmaf(vi, vi, EPSv));
        float rv  = __builtin_amdgcn_rcpf(v2);
        float gfr = fmaf(er, vr,   ei * vi)  * rv;
        float gfi = fmaf(ei, vr, -(er * vi)) * rv;
        float m2  = fmaf(gfr, gfr, gfi * gfi);
        float scf = fminf(1.f, 30.f * __builtin_amdgcn_rsqf(m2));  // m2=0 -> 1
        float tf  = LRF * scf;

        // ew (old b, old psi)
        float dbr = dr - br, dbi = di - bi;
        float ewr = fmaf(dbr, psr, -(dbi * psj)) - vr;
        float ewi = fmaf(dbr, psj,   dbi * psr)  - vi;

        // delta-v and next v  (w-clip provably inactive: |gw| <= ~0.4 << 30)
        float Dr = fmaf(ewr, sCr, -(ewi * sCi));
        float Di = fmaf(ewr, sCi,   ewi * sCr);
        vr = basr + Dr;
        vi = basi + Di;

        // state updates
        fr = fmaf(tf, gfr, fr); fi = fmaf(tf, gfi, fi);
        br = fmaf(LRB, er, br); bi = fmaf(LRB, ei, bi);

        float ff = fmaf(fr, fr, fi * fi);
        float rs = __builtin_amdgcn_rsqf(ff);
        psr = fr * rs; psj = -(fi * rs);

        ewPr = ewr; ewPi = ewi; sP = sN;

        // prefetch u_{n+2} into the (now dead) P slot
        int nn = n + 2; if (nn > NS - 1) nn = NS - 1;
        LOADU(nn, uPAr, uPAi, uPBr, uPBi);
    };

    int n = 0;
    for (int it = 0; it < 33328; ++it) {   // 3*33328 = 99984 steps
        STEP(n,     pAr,pAi,pBr,pBi,  qAr,qAi,qBr,qBi,  rAr,rAi,rBr,rBi);
        STEP(n + 1, qAr,qAi,qBr,qBi,  rAr,rAi,rBr,rBi,  pAr,pAi,pBr,pBi);
        STEP(n + 2, rAr,rAi,rBr,rBi,  pAr,pAi,pBr,pBi,  qAr,qAi,qBr,qBi);
        n += 3;
    }
    STEP(99984, pAr,pAi,pBr,pBi, qAr,qAi,qBr,qBi, rAr,rAi,rBr,rBi);  // tail
}

extern "C" void kernel_launch(void* const* d_in, const int* in_sizes, int n_in,
                              void* d_out, int out_size, void* d_ws, size_t ws_size,
                              hipStream_t stream) {
    const float* xre = (const float*)d_in[0];
    const float* xim = (const float*)d_in[1];
    float* out = (float*)d_out;
    const int NS = 99985;

    if (ws_size >= (size_t)NS * sizeof(float4)) {
        float4* tab = (float4*)d_ws;
        pre_tab<<<(NS + 255) / 256, 256, 0, stream>>>(xre, xim, tab, NS);
        ddlms_scan<true><<<1, 64, 0, stream>>>(xre, xim, tab, out);
    } else {
        ddlms_scan<false><<<1, 64, 0, stream>>>(xre, xim, nullptr, out);
    }
}

// Round 10
// 21666.414 us; speedup vs baseline: 2.7269x; 1.0792x over previous
//
#include <hip/hip_runtime.h>

typedef unsigned u2v __attribute__((ext_vector_type(2)));

// ---- XOR-butterfly reduction, all-VALU (proven bit-uniform, R5/R6/R8) ---
template<int CTRL>
__device__ __forceinline__ float dpp_xadd(float v) {
    int s = __builtin_amdgcn_update_dpp(0, __float_as_int(v), CTRL, 0xF, 0xF, true);
    return v + __int_as_float(s);
}

#if __has_builtin(__builtin_amdgcn_permlane16_swap)
__device__ __forceinline__ float xor16_add(float v) {
    u2v r = __builtin_amdgcn_permlane16_swap((unsigned)__float_as_int(v),
                                             (unsigned)__float_as_int(v),
                                             false, false);
    return __int_as_float((int)r.x) + __int_as_float((int)r.y);
}
#else
__device__ __forceinline__ float xor16_add(float v) {
    int s = __builtin_amdgcn_ds_swizzle(__float_as_int(v), 0x401F);
    return v + __int_as_float(s);
}
#endif

__device__ __forceinline__ float red32(float v) {
    v = dpp_xadd<0xB1>(v);    // lane ^ 1
    v = dpp_xadd<0x4E>(v);    // lane ^ 2
    v = dpp_xadd<0x141>(v);   // lane ^ 7
    v = dpp_xadd<0x140>(v);   // lane ^ 15
    v = xor16_add(v);         // lane ^ 16
    return v;
}

// ---- parallel precompute: s_n = LRW/(sum|u_n|^2+eps); sC_n = s_n*C_n ----
__global__ void pre_tab(const float* __restrict__ xre,
                        const float* __restrict__ xim,
                        float4* __restrict__ tab, int ns) {
    int n = blockIdx.x * blockDim.x + threadIdx.x;
    if (n >= ns) return;
    const float* ar = xre + 4 * n;
    const float* ai = xim + 4 * n;
    float un = 0.f;
    #pragma unroll 8
    for (int k = 0; k < 64; ++k) un = fmaf(ar[k], ar[k], fmaf(ai[k], ai[k], un));
    float s = (1.0f / 64.0f) / (un + 1e-8f);
    float cr = 0.f, ci = 0.f;
    if (n + 1 < ns) {
        const float* br_ = ar + 4;
        const float* bi_ = ai + 4;
        #pragma unroll 8
        for (int k = 0; k < 64; ++k) {
            cr = fmaf(ar[k], br_[k], fmaf(ai[k], bi_[k], cr));
            ci = fmaf(ar[k], bi_[k], ci);
            ci = fmaf(-ai[k], br_[k], ci);
        }
    }
    tab[n] = make_float4(s, s * cr, s * ci, 0.f);
}

// ---- DDLMS scan: one wave64; v split base+delta; distance-3 prefetch ----
template<bool PRE>
__global__ __launch_bounds__(64, 1)
void ddlms_scan(const float* __restrict__ xre,
                const float* __restrict__ xim,
                const float4* __restrict__ tab,
                float* __restrict__ out) {
    const int l = (int)threadIdx.x;
    const int m = l & 31;
    const int half = l >> 5;

    constexpr float EPSv = 1e-8f;
    constexpr float LRW  = 1.0f / 64.0f;
    constexpr float LRF  = 1.0f / 128.0f;
    constexpr float LRB  = 1.0f / 2048.0f;
    const float B1 = 0.6324555320336759f;
    const float A1 = 0.31622776601683794f;
    const float A3 = 0.9486832980505138f;

    float wAr=0.f, wAi=0.f, wBr=0.f, wBi=0.f;
    float fr=1.f, fi=0.f, br=0.f, bi=0.f;
    float psr=1.f, psj=0.f;
    float vr=0.f, vi=0.f;
    float ewPr=0.f, ewPi=0.f, sP=0.f;

    float2* __restrict__ o2 = reinterpret_cast<float2*>(out);
    const int NS = 99985;

    auto LOADU = [&](int nn, float& a, float& b_, float& c, float& d_) {
        const float* pr = xre + 4 * nn;
        const float* pi = xim + 4 * nn;
        a = pr[m]; c = pr[m + 32]; b_ = pi[m]; d_ = pi[m + 32];
    };
    auto LOADT = [&](int nn, float& s, float& cr, float& ci) {
        if constexpr (PRE) {
            float4 t = tab[nn];
            s = t.x; cr = t.y; ci = t.z;
        }
    };

    // 4 rotating u slots (slot k holds u_n with n%4==k) and 4 t slots
    float u0Ar,u0Ai,u0Br,u0Bi, u1Ar,u1Ai,u1Br,u1Bi,
          u2Ar,u2Ai,u2Br,u2Bi, u3Ar,u3Ai,u3Br,u3Bi;
    float t0s=0,t0r=0,t0i=0, t1s=0,t1r=0,t1i=0,
          t2s=0,t2r=0,t2i=0, t3s=0,t3r=0,t3i=0;

    u3Ar=u3Ai=u3Br=u3Bi=0.f;                 // uP for step 0 (sP=0)
    LOADU(0, u0Ar,u0Ai,u0Br,u0Bi);
    LOADU(1, u1Ar,u1Ai,u1Br,u1Bi);
    LOADU(2, u2Ar,u2Ai,u2Br,u2Bi);
    LOADT(0, t0s,t0r,t0i);
    LOADT(1, t1s,t1r,t1i);
    LOADT(2, t2s,t2r,t2i);

    // STEP(n): uPF = slot (n-1)%4 (read as u_{n-1}, then overwritten with
    // the u_{n+3} prefetch); uC = slot n%4 (non-PRE only); uN = slot (n+1)%4;
    // tC = t slot n%4; tF = t slot (n+3)%4.
    auto STEP = [&](int n,
        float& uPAr, float& uPAi, float& uPBr, float& uPBi,
        float& uCAr, float& uCAi, float& uCBr, float& uCBi,
        float& uNAr, float& uNAi, float& uNBr, float& uNBi,
        float& tCs, float& tCr, float& tCi,
        float& tFs, float& tFr, float& tFi) {

        // shadow: w += sP*(ewP (x) conj(uP))   (only reader of the uP slot)
        {
            float gr = ewPr * uPAr; gr = fmaf( ewPi, uPAi, gr);
            float gi = ewPi * uPAr; gi = fmaf(-ewPr, uPAi, gi);
            wAr = fmaf(sP, gr, wAr); wAi = fmaf(sP, gi, wAi);
            float hr = ewPr * uPBr; hr = fmaf( ewPi, uPBi, hr);
            float hi = ewPi * uPBr; hi = fmaf(-ewPr, uPBi, hi);
            wBr = fmaf(sP, hr, wBr); wBi = fmaf(sP, hi, wBi);
        }

        // distance-3 prefetch into the now-dead uP/tF slots
        {
            int nn = n + 3; if (nn > NS - 1) nn = NS - 1;
            LOADU(nn, uPAr, uPAi, uPBr, uPBi);
            LOADT(nn, tFs, tFr, tFi);
        }

        // shadow: base_{n+1} = red(w_n * u_{n+1})
        float basr, basi;
        {
            float prr = wAr * uNAr; prr = fmaf(-wAi, uNAi, prr);
            prr = fmaf(wBr, uNBr, prr); prr = fmaf(-wBi, uNBi, prr);
            float pri = wAr * uNAi; pri = fmaf( wAi, uNAr, pri);
            pri = fmaf(wBr, uNBi, pri); pri = fmaf( wBi, uNBr, pri);
            basr = red32(prr); basi = red32(pri);
        }

        // per-step scalars
        float sN, sCr, sCi;
        if constexpr (PRE) {
            sN = tCs; sCr = tCr; sCi = tCi;
        } else {
            float uu = uCAr * uCAr; uu = fmaf(uCAi, uCAi, uu);
            uu = fmaf(uCBr, uCBr, uu); uu = fmaf(uCBi, uCBi, uu);
            sN = LRW * __builtin_amdgcn_rcpf(red32(uu) + EPSv);
            float ccr = uCAr * uNAr; ccr = fmaf(uCAi, uNAi, ccr);
            ccr = fmaf(uCBr, uNBr, ccr); ccr = fmaf(uCBi, uNBi, ccr);
            float cci = uCAr * uNAi; cci = fmaf(-uCAi, uNAr, cci);
            cci = fmaf(uCBr, uNBi, cci); cci = fmaf(-uCBi, uNBr, cci);
            sCr = sN * red32(ccr); sCi = sN * red32(cci);
        }

        // ---- critical chain (byte-identical dataflow to R8) ----
        float kr = fmaf(vr, fr, -(vi * fi));
        float ki = fmaf(vr, fi,   vi * fr);
        float zr = kr + br, zi = ki + bi;
        if (m == 0) o2[2 * n + half] = make_float2(zr, zi);

        float magr = (fabsf(zr) > B1) ? A3 : A1;
        float dr   = (zr <= 0.f) ? -magr : magr;
        float magi = (fabsf(zi) > B1) ? A3 : A1;
        float di   = (zi <= 0.f) ? -magi : magi;

        float er = dr - zr, ei = di - zi;

        float v2  = fmaf(vr, vr, fmaf(vi, vi, EPSv));
        float rv  = __builtin_amdgcn_rcpf(v2);
        float gfr = fmaf(er, vr,   ei * vi)  * rv;
        float gfi = fmaf(ei, vr, -(er * vi)) * rv;
        float m2  = fmaf(gfr, gfr, gfi * gfi);
        float scf = fminf(1.f, 30.f * __builtin_amdgcn_rsqf(m2));
        float tf  = LRF * scf;

        float dbr = dr - br, dbi = di - bi;
        float ewr = fmaf(dbr, psr, -(dbi * psj)) - vr;
        float ewi = fmaf(dbr, psj,   dbi * psr)  - vi;

        float Dr = fmaf(ewr, sCr, -(ewi * sCi));
        float Di = fmaf(ewr, sCi,   ewi * sCr);
        vr = basr + Dr;
        vi = basi + Di;

        fr = fmaf(tf, gfr, fr); fi = fmaf(tf, gfi, fi);
        br = fmaf(LRB, er, br); bi = fmaf(LRB, ei, bi);

        float ff = fmaf(fr, fr, fi * fi);
        float rs = __builtin_amdgcn_rsqf(ff);
        psr = fr * rs; psj = -(fi * rs);

        ewPr = ewr; ewPi = ewi; sP = sN;
    };

    int n = 0;
    for (int it = 0; it < 24996; ++it) {     // 4*24996 = 99984 steps
        STEP(n+0, u3Ar,u3Ai,u3Br,u3Bi, u0Ar,u0Ai,u0Br,u0Bi,
                  u1Ar,u1Ai,u1Br,u1Bi, t0s,t0r,t0i, t3s,t3r,t3i);
        STEP(n+1, u0Ar,u0Ai,u0Br,u0Bi, u1Ar,u1Ai,u1Br,u1Bi,
                  u2Ar,u2Ai,u2Br,u2Bi, t1s,t1r,t1i, t0s,t0r,t0i);
        STEP(n+2, u1Ar,u1Ai,u1Br,u1Bi, u2Ar,u2Ai,u2Br,u2Bi,
                  u3Ar,u3Ai,u3Br,u3Bi, t2s,t2r,t2i, t1s,t1r,t1i);
        STEP(n+3, u2Ar,u2Ai,u2Br,u2Bi, u3Ar,u3Ai,u3Br,u3Bi,
                  u0Ar,u0Ai,u0Br,u0Bi, t3s,t3r,t3i, t2s,t2r,t2i);
        n += 4;
    }
    // tail step 99984 (k=0 pattern; prefetch clamps to 99984)
    STEP(99984, u3Ar,u3Ai,u3Br,u3Bi, u0Ar,u0Ai,u0Br,u0Bi,
                u1Ar,u1Ai,u1Br,u1Bi, t0s,t0r,t0i, t3s,t3r,t3i);
}

extern "C" void kernel_launch(void* const* d_in, const int* in_sizes, int n_in,
                              void* d_out, int out_size, void* d_ws, size_t ws_size,
                              hipStream_t stream) {
    const float* xre = (const float*)d_in[0];
    const float* xim = (const float*)d_in[1];
    float* out = (float*)d_out;
    const int NS = 99985;

    if (ws_size >= (size_t)NS * sizeof(float4)) {
        float4* tab = (float4*)d_ws;
        pre_tab<<<(NS + 255) / 256, 256, 0, stream>>>(xre, xim, tab, NS);
        ddlms_scan<true><<<1, 64, 0, stream>>>(xre, xim, tab, out);
    } else {
        ddlms_scan<false><<<1, 64, 0, stream>>>(xre, xim, nullptr, out);
    }
}